// Round 17
// baseline (10580.373 us; speedup 1.0000x reference)
//
#include <hip/hip_runtime.h>

// SparseGPT forward on MI355X. Round 17: bit-exact perf round.
// - attn v7: T14 async-stage (prefetch chunk c+1 to regs during compute of c),
//   single LDS buffer, wave-local softmax (R16's verified bit-exact trees).
// - GEMM: 1-D grid + bijective XCD-contiguous swizzle (m-fastest) so each
//   B-panel is owned by one XCD's L2 (lm_head overfetch 1.09GB -> ~0.2GB).
// All per-output fp32 op orders identical to passing R11-R16 (absmax 0.046875).

typedef unsigned int u32;

#define TT 2048
#define DD 1024
#define HH 16
#define DMM 4096
#define VV 32000
#define AQ 4

// ---------------- embedding ----------------
__global__ __launch_bounds__(256) void embed32_k(const int* __restrict__ idx,
    const float* __restrict__ wte, const float* __restrict__ wpe, float* __restrict__ x){
  int t = blockIdx.x, tid = threadIdx.x;
  int tok = idx[t];
  #pragma unroll
  for (int i=0;i<4;i++){
    int e = tid*4 + i;
    x[(size_t)t*DD + e] = __fadd_rn(wte[(size_t)tok*DD + e], wpe[(size_t)t*DD + e]);
  }
}

// ------- rmsnorm, XLA replica; lane-parallel tree (same pairing) -------
__global__ __launch_bounds__(64) void rms_xla_k(const float* __restrict__ x,
    const float* __restrict__ w, float* __restrict__ out){
  __shared__ float sq[1024];
  __shared__ float p5[512];
  __shared__ float fin[64];
  __shared__ float srt;
  int row = blockIdx.x, lane = threadIdx.x;
  const float* xr = x + (size_t)row*DD;
  for (int i=lane; i<1024; i+=64){ float v = xr[i]; sq[i] = __fmul_rn(v,v); }
  __syncthreads();
  for (int t=lane; t<512; t+=64)
    p5[t] = __fadd_rn(sq[2*t], sq[2*t+1]);
  __syncthreads();
  #pragma unroll
  for (int off=32; off; off>>=1){
    for (int t=lane; t<8*off; t+=64){
      int wv = t/off, ii = t - wv*off;
      p5[64*wv+ii] = __fadd_rn(p5[64*wv+ii], p5[64*wv+ii+off]);
    }
    __syncthreads();
  }
  fin[lane] = (lane<8) ? p5[64*lane] : 0.0f;
  __syncthreads();
  #pragma unroll
  for (int off=32; off; off>>=1){
    if (lane<off) fin[lane] = __fadd_rn(fin[lane], fin[lane+off]);
    __syncthreads();
  }
  if (lane==0){
    float mean = __fdiv_rn(fin[0], 1024.0f);
    srt = rsqrtf(__fadd_rn(mean, 1e-6f));
  }
  __syncthreads();
  float r = srt;
  for (int i=lane; i<1024; i+=64)
    out[(size_t)row*DD + i] = __fmul_rn(__fmul_rn(xr[i], r), w[i]);
}

// ------- GEMM: strict k-ascending single-acc FMA; BK=16 dbuf; XCD swizzle -------
// 1-D grid, nwg = nm*nn. Bijective map: XCD x (= wgid%8) gets contiguous lids,
// m-fastest within -> one XCD owns all m-blocks of each B-panel (L2-resident).
// MODE: 0 = store, 1 = f32 += (residual), 2 = gelu (OCML erff) store.
template<int MODE, int NQ>
__global__ __launch_bounds__(256) void gemm_db_k(const float* __restrict__ A,
    const float* __restrict__ B, float* __restrict__ C, int M, int N, int K, int nm){
  __shared__ float As[2][16][132];          // [buf][k][m]
  __shared__ float Bs[2][16][64*NQ+4];      // [buf][k][n]
  const int tid = threadIdx.x;
  const int tr = tid >> 4, tc = tid & 15;
  // XCD-contiguous bijective swizzle (m204)
  const int nwg = gridDim.x, w0 = blockIdx.x;
  const int qq = nwg >> 3, rr8 = nwg & 7;
  const int xcd = w0 & 7, jj = w0 >> 3;
  const int lid = xcd*qq + (xcd < rr8 ? xcd : rr8) + jj;
  const int bm = lid % nm, bn = lid / nm;
  const int m0 = bm*128, n0 = bn*(64*NQ);

  const int ar0 = tid >> 2,       af0 = tid & 3;
  const int ar1 = (256+tid) >> 2, af1 = tid & 3;
  float acc[8][4*NQ];
  #pragma unroll
  for (int i=0;i<8;i++)
    #pragma unroll
    for (int j=0;j<4*NQ;j++) acc[i][j] = 0.0f;

  const int niter = K >> 4;
  {
    float4 va0 = *(const float4*)&A[(size_t)(m0+ar0)*K + 4*af0];
    float4 va1 = *(const float4*)&A[(size_t)(m0+ar1)*K + 4*af1];
    As[0][4*af0+0][ar0]=va0.x; As[0][4*af0+1][ar0]=va0.y; As[0][4*af0+2][ar0]=va0.z; As[0][4*af0+3][ar0]=va0.w;
    As[0][4*af1+0][ar1]=va1.x; As[0][4*af1+1][ar1]=va1.y; As[0][4*af1+2][ar1]=va1.z; As[0][4*af1+3][ar1]=va1.w;
    if (NQ==2){
      int r0 = tid>>5, c40 = tid&31;
      int r1 = (256+tid)>>5, c41 = tid&31;
      *(float4*)&Bs[0][r0][4*c40] = *(const float4*)&B[(size_t)r0*N + n0 + 4*c40];
      *(float4*)&Bs[0][r1][4*c41] = *(const float4*)&B[(size_t)r1*N + n0 + 4*c41];
    } else {
      int r0 = tid>>4, c40 = tid&15;
      *(float4*)&Bs[0][r0][4*c40] = *(const float4*)&B[(size_t)r0*N + n0 + 4*c40];
    }
  }
  __syncthreads();

  for (int t=0; t<niter; ++t){
    const int cur = t & 1;
    float4 va0, va1, vb0, vb1;
    if (t+1 < niter){
      int kk = (t+1) << 4;
      va0 = *(const float4*)&A[(size_t)(m0+ar0)*K + kk + 4*af0];
      va1 = *(const float4*)&A[(size_t)(m0+ar1)*K + kk + 4*af1];
      if (NQ==2){
        int r0 = tid>>5, c40 = tid&31;
        int r1 = (256+tid)>>5;
        vb0 = *(const float4*)&B[(size_t)(kk+r0)*N + n0 + 4*c40];
        vb1 = *(const float4*)&B[(size_t)(kk+r1)*N + n0 + 4*c40];
      } else {
        int r0 = tid>>4, c40 = tid&15;
        vb0 = *(const float4*)&B[(size_t)(kk+r0)*N + n0 + 4*c40];
      }
    }
    #pragma unroll 4
    for (int k=0; k<16; ++k){
      float4 a0 = *(const float4*)&As[cur][k][4*tr];
      float4 a1 = *(const float4*)&As[cur][k][64 + 4*tr];
      float4 b0 = *(const float4*)&Bs[cur][k][4*tc];
      float av[8] = {a0.x,a0.y,a0.z,a0.w, a1.x,a1.y,a1.z,a1.w};
      float bv[4*NQ];
      bv[0]=b0.x; bv[1]=b0.y; bv[2]=b0.z; bv[3]=b0.w;
      if (NQ==2){
        float4 b1 = *(const float4*)&Bs[cur][k][64 + 4*tc];
        bv[4]=b1.x; bv[5]=b1.y; bv[6]=b1.z; bv[7]=b1.w;
      }
      #pragma unroll
      for (int i=0;i<8;i++)
        #pragma unroll
        for (int j=0;j<4*NQ;j++)
          acc[i][j] = __builtin_fmaf(av[i], bv[j], acc[i][j]);
    }
    if (t+1 < niter){
      const int nxt = cur ^ 1;
      As[nxt][4*af0+0][ar0]=va0.x; As[nxt][4*af0+1][ar0]=va0.y; As[nxt][4*af0+2][ar0]=va0.z; As[nxt][4*af0+3][ar0]=va0.w;
      As[nxt][4*af1+0][ar1]=va1.x; As[nxt][4*af1+1][ar1]=va1.y; As[nxt][4*af1+2][ar1]=va1.z; As[nxt][4*af1+3][ar1]=va1.w;
      if (NQ==2){
        int r0 = tid>>5, c40 = tid&31;
        int r1 = (256+tid)>>5;
        *(float4*)&Bs[nxt][r0][4*c40] = vb0;
        *(float4*)&Bs[nxt][r1][4*c40] = vb1;
      } else {
        int r0 = tid>>4, c40 = tid&15;
        *(float4*)&Bs[nxt][r0][4*c40] = vb0;
      }
    }
    __syncthreads();
  }

  #pragma unroll
  for (int i=0;i<8;i++){
    int row = m0 + (i>>2)*64 + 4*tr + (i&3);
    #pragma unroll
    for (int jq=0;jq<NQ;jq++){
      size_t off = (size_t)row*N + n0 + jq*64 + 4*tc;
      #pragma unroll
      for (int e=0;e<4;e++){
        float vv = acc[i][jq*4+e];
        if (MODE==0){
          C[off+e] = vv;
        } else if (MODE==1){
          C[off+e] = __fadd_rn(C[off+e], vv);
        } else {
          float t2 = __fdiv_rn(vv, 1.41421356f);
          float g = erff(t2);
          C[off+e] = __fmul_rn(__fmul_rn(0.5f, vv), __fadd_rn(1.0f, g));
        }
      }
    }
  }
}

// ---------------- attention v7: T14 async-stage + wave-local softmax ----------------
// Wave w owns q = q0+w. Slot layout (R11): arr[w][0]=sink-exp, [1+kv]=val.
__global__ __launch_bounds__(256) void attn_v7_k(const float* __restrict__ qkv,
    const float* __restrict__ sink, float* __restrict__ y){
  __shared__ float arr[AQ][2049];       // 32.0KiB
  __shared__ float Ks[64][68];          // 17.0KiB (K chunks, then V chunks)
  const int tid = threadIdx.x;
  const int lane = tid & 63, wv = tid >> 6;
  const int h = blockIdx.y, q0 = blockIdx.x*AQ;
  const int qa_w = q0 + wv;
  const int qmax = q0 + AQ - 1;
  const int nch = (qmax >> 6) + 1;
  const float snk = sink[h];
  const int sr = tid >> 4, sc4 = tid & 15;   // staging row/col4 per thread (it-strided)

  // zero-init arr (masked slots must be exact 0)
  #pragma unroll
  for (int qi=0;qi<AQ;qi++)
    for (int s=tid; s<2049; s+=256) arr[qi][s] = 0.0f;

  // preload Q row into regs
  float qv[64];
  {
    const float* qr = qkv + (size_t)qa_w*3072 + h*64;
    #pragma unroll
    for (int c4=0;c4<16;c4++){
      float4 v = *(const float4*)&qr[4*c4];
      qv[4*c4]=v.x; qv[4*c4+1]=v.y; qv[4*c4+2]=v.z; qv[4*c4+3]=v.w;
    }
  }

  // ---- scores: async-staged K chunks ----
  float ml = -3.402823466e38f;
  float4 ld[4];
  #pragma unroll
  for (int it=0; it<4; ++it)                 // prologue: chunk 0
    ld[it] = *(const float4*)&qkv[(size_t)(sr + it*16)*3072 + 1024 + h*64 + 4*sc4];
  for (int c=0; c<nch; ++c){
    int base = c << 6;
    #pragma unroll
    for (int it=0; it<4; ++it)               // write staged chunk
      *(float4*)&Ks[sr + it*16][4*sc4] = ld[it];
    __syncthreads();
    if (c+1 < nch){                          // issue next chunk (hidden by compute)
      int nb = base + 64;
      #pragma unroll
      for (int it=0; it<4; ++it){
        int kr = nb + sr + it*16;
        if (kr < TT)
          ld[it] = *(const float4*)&qkv[(size_t)kr*3072 + 1024 + h*64 + 4*sc4];
      }
    }
    int kv = base + lane;
    if (kv <= qa_w){
      float s = 0.0f;
      #pragma unroll
      for (int c4=0;c4<16;c4++){             // d-ascending FMA chain (R11 order)
        float4 kf = *(const float4*)&Ks[lane][4*c4];
        s = __builtin_fmaf(qv[4*c4  ], kf.x, s);
        s = __builtin_fmaf(qv[4*c4+1], kf.y, s);
        s = __builtin_fmaf(qv[4*c4+2], kf.z, s);
        s = __builtin_fmaf(qv[4*c4+3], kf.w, s);
      }
      s = __fmul_rn(s, 0.125f);
      arr[wv][1+kv] = s;
      ml = fmaxf(ml, s);
    }
    __syncthreads();
  }

  // prologue V chunk 0 (overlaps softmax phase)
  #pragma unroll
  for (int it=0; it<4; ++it)
    ld[it] = *(const float4*)&qkv[(size_t)(sr + it*16)*3072 + 2048 + h*64 + 4*sc4];

  // ---- wave max (order-free) + sink ----
  #pragma unroll
  for (int off=1; off<64; off<<=1) ml = fmaxf(ml, __shfl_xor(ml, off, 64));
  float m = fmaxf(ml, snk);

  // ---- exp (OCML expf) over own wave's slots; sink-exp in slot 0 ----
  for (int s=1+lane; s<=1+qa_w; s+=64)
    arr[wv][s] = expf(__fsub_rn(arr[wv][s], m));
  if (lane==0) arr[wv][0] = expf(__fsub_rn(snk, m));

  // ---- denominator, wave-local (R11 strided-512 chains + exact tree) ----
  float pg[8];
  #pragma unroll
  for (int g=0; g<8; ++g){
    int t = lane + 64*g;
    float a = 0.0f;
    for (int s=t; s<2049; s+=512) a = __fadd_rn(a, arr[wv][s]);
    pg[g] = a;
  }
  #pragma unroll
  for (int g=0; g<8; ++g){
    #pragma unroll
    for (int off=32; off; off>>=1)
      pg[g] = __fadd_rn(pg[g], __shfl_down(pg[g], off, 64));
  }
  float den;
  {
    float t04 = __fadd_rn(pg[0], pg[4]);
    float t26 = __fadd_rn(pg[2], pg[6]);
    float t15 = __fadd_rn(pg[1], pg[5]);
    float t37 = __fadd_rn(pg[3], pg[7]);
    float d0 = __fadd_rn(__fadd_rn(t04, t26), __fadd_rn(t15, t37));
    den = __shfl(d0, 0, 64);
  }

  // ---- probs in place (own wave's slots) ----
  for (int s=1+lane; s<=1+qa_w; s+=64)
    arr[wv][s] = __fdiv_rn(arr[wv][s], den);

  // ---- PV: async-staged V chunks; kv-ascending single-acc chain ----
  float acc = 0.0f;
  for (int c=0; c<nch; ++c){
    int base = c << 6;
    __syncthreads();                          // prev chunk consumed
    #pragma unroll
    for (int it=0; it<4; ++it)
      *(float4*)&Ks[sr + it*16][4*sc4] = ld[it];
    __syncthreads();
    if (c+1 < nch){
      int nb = base + 64;
      #pragma unroll
      for (int it=0; it<4; ++it){
        int kr = nb + sr + it*16;
        if (kr < TT)
          ld[it] = *(const float4*)&qkv[(size_t)kr*3072 + 2048 + h*64 + 4*sc4];
      }
    }
    int lim = qa_w - base; if (lim > 63) lim = 63;
    int j = 0;
    for (; j + 8 <= lim + 1; j += 8){
      #pragma unroll
      for (int e=0;e<8;e++)
        acc = __builtin_fmaf(arr[wv][1+base+j+e], Ks[j+e][lane], acc);
    }
    for (; j <= lim; ++j)
      acc = __builtin_fmaf(arr[wv][1+base+j], Ks[j][lane], acc);
  }
  y[(size_t)qa_w*DD + h*64 + lane] = acc;
}

// -------- abs top-k on f32 bits: exact radix select; zero in place --------
__global__ __launch_bounds__(256) void topk32_k(float* __restrict__ h,
    const int* __restrict__ kptr){
  const int row = blockIdx.x, tid = threadIdx.x;
  __shared__ int suf[256];
  __shared__ int s_sel, s_k;
  float* hr = h + (size_t)row*DMM;
  int kk = kptr[0];
  u32 prefix = 0u;
  for (int pass=0; pass<4; pass++){
    int shift = 24 - 8*pass;
    u32 hi_mask = pass ? (0xFFFFFFFFu << (shift+8)) : 0u;
    suf[tid] = 0;
    __syncthreads();
    for (int i=0;i<16;i++){
      u32 b = __float_as_uint(hr[tid + 256*i]) & 0x7fffffffu;
      if ((b & hi_mask) == prefix) atomicAdd(&suf[(b>>shift)&255], 1);
    }
    __syncthreads();
    for (int s=1;s<256;s<<=1){
      int v2 = (tid+s<256) ? suf[tid+s] : 0;
      __syncthreads();
      suf[tid] += v2;
      __syncthreads();
    }
    int nxt = (tid<255) ? suf[tid+1] : 0;
    if (suf[tid] >= kk && nxt < kk){ s_sel = tid; s_k = kk - nxt; }
    __syncthreads();
    prefix |= ((u32)s_sel) << shift;
    kk = s_k;
    __syncthreads();
  }
  for (int i=0;i<16;i++){
    int e = tid + 256*i;
    u32 b = __float_as_uint(hr[e]) & 0x7fffffffu;
    if (b < prefix) hr[e] = 0.0f;
  }
}

// ---------------- host launcher ----------------
extern "C" void kernel_launch(void* const* d_in, const int* in_sizes, int n_in,
                              void* d_out, int out_size, void* d_ws, size_t ws_size,
                              hipStream_t stream){
  const int*   idx  = (const int*)  d_in[0];
  const float* wte  = (const float*)d_in[1];
  const float* wpe  = (const float*)d_in[2];
  const float* ln1  = (const float*)d_in[3];
  const float* ln2  = (const float*)d_in[4];
  const float* Wa   = (const float*)d_in[5];
  const float* Wap  = (const float*)d_in[6];
  const float* Wf   = (const float*)d_in[7];
  const float* Wp   = (const float*)d_in[8];
  const float* sink = (const float*)d_in[9];
  const float* lnf  = (const float*)d_in[10];
  const float* lmw  = (const float*)d_in[11];
  const int*   kptr = (const int*)  d_in[12];
  (void)in_sizes; (void)n_in; (void)out_size; (void)ws_size;

  // ---- workspace: 80 MB, all fp32, no aliasing ----
  char* w = (char*)d_ws;
  float* x   = (float*)(w);                 // [0, 8M)
  float* xn  = (float*)(w + 8388608);       // [8M, 16M)
  float* qkv = (float*)(w + 16777216);      // [16M, 40M)
  float* y   = (float*)(w + 41943040);      // [40M, 48M)
  float* h   = (float*)(w + 50331648);      // [48M, 80M)

  embed32_k<<<TT, 256, 0, stream>>>(idx, wte, wpe, x);

  for (int l=0; l<4; l++){
    rms_xla_k<<<TT, 64, 0, stream>>>(x, ln1 + l*DD, xn);
    gemm_db_k<0,2><<<(3072/128)*(TT/128), 256, 0, stream>>>(xn, Wa + (size_t)l*1024*3072, qkv, TT, 3072, 1024, TT/128);
    attn_v7_k<<<dim3(TT/AQ, HH), 256, 0, stream>>>(qkv, sink + l*HH, y);
    gemm_db_k<1,1><<<(1024/64)*(TT/128), 256, 0, stream>>>(y, Wap + (size_t)l*1024*1024, x, TT, 1024, 1024, TT/128);
    rms_xla_k<<<TT, 64, 0, stream>>>(x, ln2 + l*DD, xn);
    gemm_db_k<2,2><<<(4096/128)*(TT/128), 256, 0, stream>>>(xn, Wf + (size_t)l*1024*4096, h, TT, 4096, 1024, TT/128);
    topk32_k<<<TT, 256, 0, stream>>>(h, kptr);
    gemm_db_k<1,1><<<(1024/64)*(TT/128), 256, 0, stream>>>(h, Wp + (size_t)l*4096*1024, x, TT, 1024, 4096, TT/128);
  }

  rms_xla_k<<<TT, 64, 0, stream>>>(x, lnf, xn);
  gemm_db_k<0,2><<<(VV/128)*(TT/128), 256, 0, stream>>>(xn, lmw, (float*)d_out, TT, VV, 1024, TT/128);
}